// Round 5
// baseline (19043.878 us; speedup 1.0000x reference)
//
#include <hip/hip_runtime.h>
#include <math.h>

#define Bn   128
#define Sn   336
#define INd  64
#define Hn   1024
#define Tn   96
#define G4   4096
#define KCE  34     // enc k-chunks: [x(64) | h(1024)]
#define KCD  65     // dec k-chunks: [ctx(1024) | h(1024) | prev_y | pad]
#define KCQ  32     // attn query k-chunks

typedef __attribute__((ext_vector_type(8))) short short8;
typedef __attribute__((ext_vector_type(4))) float floatx4;

__device__ __forceinline__ float sigmoidf_(float x){ return 1.0f/(1.0f+expf(-x)); }

__device__ __forceinline__ unsigned short f2bf(float f){
    union { float f; unsigned u; } v; v.f = f;
    unsigned r = v.u + 0x7fffu + ((v.u >> 16) & 1u);
    return (unsigned short)(r >> 16);
}
__device__ __forceinline__ float bflo(unsigned u){ union{unsigned u; float f;} v; v.u = u << 16;        return v.f; }
__device__ __forceinline__ float bfhi(unsigned u){ union{unsigned u; float f;} v; v.u = u & 0xffff0000u; return v.f; }
__device__ __forceinline__ void unpack8(uint4 v, float* f){
    f[0]=bflo(v.x); f[1]=bfhi(v.x); f[2]=bflo(v.y); f[3]=bfhi(v.y);
    f[4]=bflo(v.z); f[5]=bfhi(v.z); f[6]=bflo(v.w); f[7]=bfhi(v.w);
}

// ===================== fragment-order packing ==============================
// B-fragment subtile s, chunk kc: [s][kc][lane(64)][8];
// lane l: col c=l&15, k = kc*32 + (l>>4)*8 + j. LSTM: gate = s&3, unit = (s>>2)*16+c.
__global__ void pack_encf(const float* __restrict__ Wih, const float* __restrict__ Whh,
                          const float* __restrict__ bih, const float* __restrict__ bhh,
                          unsigned short* __restrict__ Wp, float* __restrict__ bc){
    long n = (long)256*KCE*512;
    for (long idx = (long)blockIdx.x*256 + threadIdx.x; idx < n; idx += (long)gridDim.x*256){
        int j = (int)(idx & 7), l = (int)((idx >> 3) & 63);
        int kc = (int)((idx >> 9) % KCE);
        int s  = (int)(idx / (KCE*512));
        int c = l & 15, kg = l >> 4;
        int k = kc*32 + kg*8 + j;
        int gate = s & 3, unit = (s >> 2)*16 + c;
        int orig = gate*Hn + unit;
        float v = (k < INd) ? Wih[orig*INd + k] : Whh[(size_t)orig*Hn + (k - INd)];
        Wp[idx] = f2bf(v);
    }
    int tid = blockIdx.x*256 + threadIdx.x;
    if (tid < G4){
        int g = (tid >> 4) & 3, u = (tid >> 6)*16 + (tid & 15);
        int orig = g*Hn + u;
        bc[tid] = bih[orig] + bhh[orig];
    }
}

__global__ void pack_decf(const float* __restrict__ Wih, const float* __restrict__ Whh,
                          const float* __restrict__ bih, const float* __restrict__ bhh,
                          unsigned short* __restrict__ Wp, float* __restrict__ bc){
    long n = (long)256*KCD*512;
    for (long idx = (long)blockIdx.x*256 + threadIdx.x; idx < n; idx += (long)gridDim.x*256){
        int j = (int)(idx & 7), l = (int)((idx >> 3) & 63);
        int kc = (int)((idx >> 9) % KCD);
        int s  = (int)(idx / (KCD*512));
        int c = l & 15, kg = l >> 4;
        int k = kc*32 + kg*8 + j;
        int gate = s & 3, unit = (s >> 2)*16 + c;
        int orig = gate*Hn + unit;
        float v;
        if (k < Hn)          v = Wih[(size_t)orig*(Hn+1) + 1 + k];     // ctx
        else if (k < 2*Hn)   v = Whh[(size_t)orig*Hn + (k - Hn)];      // h
        else if (k == 2*Hn)  v = Wih[(size_t)orig*(Hn+1)];             // prev_y
        else                 v = 0.0f;                                  // pad
        Wp[idx] = f2bf(v);
    }
    int tid = blockIdx.x*256 + threadIdx.x;
    if (tid < G4){
        int g = (tid >> 4) & 3, u = (tid >> 6)*16 + (tid & 15);
        int orig = g*Hn + u;
        bc[tid] = bih[orig] + bhh[orig];
    }
}

__global__ void pack_attnf(const float* __restrict__ w, unsigned short* __restrict__ Wp){
    int n = 64*KCQ*512;
    for (int idx = blockIdx.x*256 + threadIdx.x; idx < n; idx += gridDim.x*256){
        int j = idx & 7, l = (idx >> 3) & 63;
        int kc = (idx >> 9) & 31;
        int s  = idx >> 14;
        int nn = s*16 + (l & 15);
        int k = kc*32 + (l >> 4)*8 + j;
        Wp[idx] = f2bf(w[(size_t)nn*Hn + k]);
    }
}

// src A-fragments: [t][rg(8)][kc(2)][lane][8]; row b = rg*16 + (l&15)
__global__ void conv_srcf(const float* __restrict__ s, unsigned short* __restrict__ d){
    int n = Sn*8*2*512;
    for (int idx = blockIdx.x*256 + threadIdx.x; idx < n; idx += gridDim.x*256){
        int j = idx & 7, l = (idx >> 3) & 63;
        int kc = (idx >> 9) & 1, rg = (idx >> 10) & 7, t = idx >> 13;
        int b = rg*16 + (l & 15);
        int k = kc*32 + (l >> 4)*8 + j;
        d[idx] = f2bf(s[((size_t)b*Sn + t)*INd + k]);
    }
}

__global__ void init_ws(unsigned short* __restrict__ hf0, float* __restrict__ cfrag,
                        unsigned short* __restrict__ A0, unsigned short* __restrict__ A1){
    for (int i = blockIdx.x*256 + threadIdx.x; i < 8*KCD*512; i += gridDim.x*256){
        A0[i] = 0; A1[i] = 0;
        if (i < 8*32*512) hf0[i] = 0;
        if (i < Bn*Hn) cfrag[i] = 0.0f;
    }
}

// ===================== encoder step: M=64/wave, B re-read x2 ===============
// grid (2,64), 64 threads (1 wave). Wave: rows mh*64..+63, cols y*16 units x 4 gates.
__global__ __launch_bounds__(64)
void enc_step(const unsigned short* __restrict__ srcfrag,  // [336][8][2][512]
              const unsigned short* __restrict__ hin,      // [8][32][512]
              const unsigned short* __restrict__ Wf,       // [256][KCE][512]
              const float* __restrict__ bc, float* __restrict__ cfrag,
              unsigned short* __restrict__ hout,           // [8][32][512]
              unsigned short* __restrict__ enco,
              unsigned short* __restrict__ adec0,          // [8][KCD][512]
              int t, int last)
{
    const int l = threadIdx.x;
    const int mh = blockIdx.x, y = blockIdx.y;
    const unsigned short* Bf = Wf + (size_t)(4*y)*KCE*512 + (size_t)l*8;
    floatx4 acc[4][4];   // [gate-subtile][rg_i]
    #pragma unroll
    for (int s = 0; s < 4; s++)
        #pragma unroll
        for (int i = 0; i < 4; i++) acc[s][i] = (floatx4){0,0,0,0};

    #pragma unroll
    for (int kc = 0; kc < 2; kc++){
        short8 b0 = *(const short8*)(Bf + (0*KCE + kc)*512);
        short8 b1 = *(const short8*)(Bf + (1*KCE + kc)*512);
        short8 b2 = *(const short8*)(Bf + (2*KCE + kc)*512);
        short8 b3 = *(const short8*)(Bf + (3*KCE + kc)*512);
        #pragma unroll
        for (int i = 0; i < 4; i++){
            short8 a = *(const short8*)(srcfrag + ((((size_t)t*8 + mh*4 + i)*2 + kc)*64 + l)*8);
            acc[0][i] = __builtin_amdgcn_mfma_f32_16x16x32_bf16(a, b0, acc[0][i], 0, 0, 0);
            acc[1][i] = __builtin_amdgcn_mfma_f32_16x16x32_bf16(a, b1, acc[1][i], 0, 0, 0);
            acc[2][i] = __builtin_amdgcn_mfma_f32_16x16x32_bf16(a, b2, acc[2][i], 0, 0, 0);
            acc[3][i] = __builtin_amdgcn_mfma_f32_16x16x32_bf16(a, b3, acc[3][i], 0, 0, 0);
        }
    }
    #pragma unroll 2
    for (int kc = 0; kc < 32; kc++){
        short8 b0 = *(const short8*)(Bf + (0*KCE + kc + 2)*512);
        short8 b1 = *(const short8*)(Bf + (1*KCE + kc + 2)*512);
        short8 b2 = *(const short8*)(Bf + (2*KCE + kc + 2)*512);
        short8 b3 = *(const short8*)(Bf + (3*KCE + kc + 2)*512);
        #pragma unroll
        for (int i = 0; i < 4; i++){
            short8 a = *(const short8*)(hin + (((size_t)(mh*4 + i)*32 + kc)*64 + l)*8);
            acc[0][i] = __builtin_amdgcn_mfma_f32_16x16x32_bf16(a, b0, acc[0][i], 0, 0, 0);
            acc[1][i] = __builtin_amdgcn_mfma_f32_16x16x32_bf16(a, b1, acc[1][i], 0, 0, 0);
            acc[2][i] = __builtin_amdgcn_mfma_f32_16x16x32_bf16(a, b2, acc[2][i], 0, 0, 0);
            acc[3][i] = __builtin_amdgcn_mfma_f32_16x16x32_bf16(a, b3, acc[3][i], 0, 0, 0);
        }
    }

    const int col = l & 15, q = l >> 4;
    const int u = y*16 + col;
    const float bi  = bc[y*64 + col];
    const float bf_ = bc[y*64 + 16 + col];
    const float bg  = bc[y*64 + 32 + col];
    const float bo  = bc[y*64 + 48 + col];
    const int lsh = ((u >> 3) & 3) * 16;
    #pragma unroll
    for (int i = 0; i < 4; i++){
        #pragma unroll
        for (int r = 0; r < 4; r++){
            const int m = mh*64 + i*16 + q*4 + r;
            float gi = acc[0][i][r] + bi;
            float gf = acc[1][i][r] + bf_;
            float gg = acc[2][i][r] + bg;
            float go = acc[3][i][r] + bo;
            const int cidx = ((((y*2 + mh)*4 + i)*4 + r)*64) + l;
            float co = cfrag[cidx];
            float cn = sigmoidf_(gf)*co + sigmoidf_(gi)*tanhf(gg);
            cfrag[cidx] = cn;
            float hv = sigmoidf_(go)*tanhf(cn);
            unsigned short hb = f2bf(hv);
            const int lanep = q*4 + r + lsh;
            hout[(((size_t)(mh*4 + i)*32 + (u >> 5))*64 + lanep)*8 + (u & 7)] = hb;
            enco[((size_t)m*Sn + t)*Hn + u] = hb;
            if (last) adec0[(((size_t)(mh*4 + i)*KCD + 32 + (u >> 5))*64 + lanep)*8 + (u & 7)] = hb;
        }
    }
}

// ===================== decoder LSTM step: M=64/wave ========================
__global__ __launch_bounds__(64)
void dec_step(const unsigned short* __restrict__ Ac,       // [8][KCD][512]
              const unsigned short* __restrict__ Wf,       // [256][KCD][512]
              const float* __restrict__ bc, float* __restrict__ cfrag,
              unsigned short* __restrict__ An)              // next A h-slot
{
    const int l = threadIdx.x;
    const int mh = blockIdx.x, y = blockIdx.y;
    const unsigned short* Bf = Wf + (size_t)(4*y)*KCD*512 + (size_t)l*8;
    const unsigned short* Af = Ac + ((size_t)(mh*4)*KCD*64 + l)*8;
    floatx4 acc[4][4];
    #pragma unroll
    for (int s = 0; s < 4; s++)
        #pragma unroll
        for (int i = 0; i < 4; i++) acc[s][i] = (floatx4){0,0,0,0};

    #pragma unroll 2
    for (int kc = 0; kc < KCD; kc++){
        short8 b0 = *(const short8*)(Bf + (0*KCD + kc)*512);
        short8 b1 = *(const short8*)(Bf + (1*KCD + kc)*512);
        short8 b2 = *(const short8*)(Bf + (2*KCD + kc)*512);
        short8 b3 = *(const short8*)(Bf + (3*KCD + kc)*512);
        #pragma unroll
        for (int i = 0; i < 4; i++){
            short8 a = *(const short8*)(Af + ((size_t)(i*KCD + kc)*64)*8);
            acc[0][i] = __builtin_amdgcn_mfma_f32_16x16x32_bf16(a, b0, acc[0][i], 0, 0, 0);
            acc[1][i] = __builtin_amdgcn_mfma_f32_16x16x32_bf16(a, b1, acc[1][i], 0, 0, 0);
            acc[2][i] = __builtin_amdgcn_mfma_f32_16x16x32_bf16(a, b2, acc[2][i], 0, 0, 0);
            acc[3][i] = __builtin_amdgcn_mfma_f32_16x16x32_bf16(a, b3, acc[3][i], 0, 0, 0);
        }
    }

    const int col = l & 15, q = l >> 4;
    const int u = y*16 + col;
    const float bi  = bc[y*64 + col];
    const float bf_ = bc[y*64 + 16 + col];
    const float bg  = bc[y*64 + 32 + col];
    const float bo  = bc[y*64 + 48 + col];
    const int lsh = ((u >> 3) & 3) * 16;
    #pragma unroll
    for (int i = 0; i < 4; i++){
        #pragma unroll
        for (int r = 0; r < 4; r++){
            float gi = acc[0][i][r] + bi;
            float gf = acc[1][i][r] + bf_;
            float gg = acc[2][i][r] + bg;
            float go = acc[3][i][r] + bo;
            const int cidx = ((((y*2 + mh)*4 + i)*4 + r)*64) + l;
            float co = cfrag[cidx];
            float cn = sigmoidf_(gf)*co + sigmoidf_(gi)*tanhf(gg);
            cfrag[cidx] = cn;
            float hv = sigmoidf_(go)*tanhf(cn);
            const int lanep = q*4 + r + lsh;
            An[(((size_t)(mh*4 + i)*KCD + 32 + (u >> 5))*64 + lanep)*8 + (u & 7)] = f2bf(hv);
        }
    }
}

// ===================== attention query GEMM (unchanged) ====================
__global__ __launch_bounds__(128)
void attnq_step(const unsigned short* __restrict__ Ac, const unsigned short* __restrict__ Wf,
                unsigned short* __restrict__ qout)
{
    const int tid = threadIdx.x, l = tid & 63, w = tid >> 6;
    const int rg = blockIdx.x*2 + w;
    const int m0 = rg*16;
    const int y = blockIdx.y;
    const unsigned short* Bf = Wf + (size_t)y*KCQ*512 + l*8;
    const unsigned short* Af = Ac + ((size_t)rg*KCD + 32)*512 + l*8;
    floatx4 acc = {0,0,0,0};
    #pragma unroll 8
    for (int kc = 0; kc < KCQ; kc++){
        short8 a = *(const short8*)(Af + kc*512);
        short8 b = *(const short8*)(Bf + kc*512);
        acc = __builtin_amdgcn_mfma_f32_16x16x32_bf16(a, b, acc, 0, 0, 0);
    }
    const int col = l & 15, q = l >> 4;
    #pragma unroll
    for (int r = 0; r < 4; r++){
        const int m = m0 + q*4 + r;
        qout[(size_t)m*Hn + y*16 + col] = f2bf(acc[r]);
    }
}

// ===================== fused attention: online softmax + ctx + fc ==========
// block per b, 512 thr = 8 waves; wave w handles s = w, w+8, ... (42 rows).
// Also computes fc(prev h) -> out[d-1] + prev_y slot (d>0).
__global__ __launch_bounds__(512)
void fattn_kernel(const unsigned short* __restrict__ q,    // [128][1024]
                  const unsigned short* __restrict__ enc,  // [128][336][1024]
                  unsigned short* __restrict__ Ac,         // fragment A buffer
                  const float* __restrict__ fcW, const float* __restrict__ fcb,
                  float* __restrict__ out, int d)
{
    __shared__ float ctxl[8*1024];
    __shared__ float mred[8], lred[8];
    __shared__ float fcred[128];
    const int b = blockIdx.x;
    const int tid = threadIdx.x, w = tid >> 6, l = tid & 63;

    float qv[16];
    {
        const uint4* qp = (const uint4*)(q + (size_t)b*Hn) + l*2;
        uint4 q0 = qp[0], q1 = qp[1];
        unpack8(q0, qv); unpack8(q1, qv + 8);
    }
    float m = -1e30f, lsum = 0.0f;
    float cacc[16];
    #pragma unroll
    for (int i = 0; i < 16; i++) cacc[i] = 0.0f;

    const uint4* ebase = (const uint4*)(enc + (size_t)b*Sn*Hn) + l*2;
    for (int s = w; s < Sn; s += 8){
        uint4 e0 = ebase[(size_t)s*128];
        uint4 e1 = ebase[(size_t)s*128 + 1];
        float ev[16];
        unpack8(e0, ev); unpack8(e1, ev + 8);
        float part = 0.0f;
        #pragma unroll
        for (int i = 0; i < 16; i++) part = fmaf(qv[i], ev[i], part);
        #pragma unroll
        for (int off = 32; off; off >>= 1) part += __shfl_down(part, off);
        float e = __shfl(part, 0);
        float mn = fmaxf(m, e);
        float corr = expf(m - mn);
        float p = expf(e - mn);
        lsum = lsum*corr + p;
        if (corr != 1.0f){
            #pragma unroll
            for (int i = 0; i < 16; i++) cacc[i] *= corr;
        }
        #pragma unroll
        for (int i = 0; i < 16; i++) cacc[i] = fmaf(p, ev[i], cacc[i]);
        m = mn;
    }
    if (l == 0){ mred[w] = m; lred[w] = lsum; }
    __syncthreads();
    float M = mred[0];
    #pragma unroll
    for (int k = 1; k < 8; k++) M = fmaxf(M, mred[k]);
    float corr = expf(m - M);
    // transposed store: element l*16+j at [w*1024 + j*64 + l] (conflict-free)
    #pragma unroll
    for (int j = 0; j < 16; j++) ctxl[w*1024 + j*64 + l] = cacc[j]*corr;
    __syncthreads();
    float L = 0.0f;
    #pragma unroll
    for (int k = 0; k < 8; k++) L += lred[k]*expf(mred[k] - M);
    float invL = 1.0f / L;

    // each thread: elements 2*tid, 2*tid+1 -> ctx fragment store (4B)
    {
        const int u0 = 2*tid;
        float s0 = 0.0f, s1 = 0.0f;
        #pragma unroll
        for (int k = 0; k < 8; k++){
            s0 += ctxl[k*1024 + (u0 & 15)*64 + (u0 >> 4)];
            s1 += ctxl[k*1024 + ((u0+1) & 15)*64 + ((u0+1) >> 4)];
        }
        ushort2 cv; cv.x = f2bf(s0*invL); cv.y = f2bf(s1*invL);
        const int kc = u0 >> 5;
        const int lanep = (b & 15) + ((u0 >> 3) & 3)*16;
        *(ushort2*)(Ac + ((((size_t)(b >> 4))*KCD + kc)*64 + lanep)*8 + (u0 & 7)) = cv;
    }

    // fc of h currently in Ac h-slot (result of previous dec_step)
    float part = 0.0f;
    if (tid < 128){
        const unsigned short* hp = Ac + ((((size_t)(b >> 4))*KCD + 32 + (tid >> 2))*64
                                         + (b & 15) + (tid & 3)*16)*8;
        uint4 hv = *(const uint4*)hp;
        float hf[8]; unpack8(hv, hf);
        #pragma unroll
        for (int j = 0; j < 8; j++) part = fmaf(hf[j], fcW[tid*8 + j], part);
    }
    __syncthreads();   // ctxl reads done before fcred reuse (separate array, but keep ordering)
    if (tid < 128) fcred[tid] = part;
    __syncthreads();
    for (int o = 64; o; o >>= 1){
        if (tid < o && tid + o < 128) fcred[tid] += fcred[tid + o];
        __syncthreads();
    }
    if (tid == 0 && d > 0){
        float p = fcred[0] + fcb[0];
        out[b*Tn + (d - 1)] = p;
        Ac[(((size_t)(b >> 4))*KCD + 64)*512 + (b & 15)*8] = f2bf(p);
    }
}

// ===================== final fc ============================================
__global__ __launch_bounds__(128)
void fc_final(const unsigned short* __restrict__ A, const float* __restrict__ fcW,
              const float* __restrict__ fcb, float* __restrict__ out){
    __shared__ float red[128];
    const int b = blockIdx.x, tid = threadIdx.x;
    const unsigned short* hp = A + ((((size_t)(b >> 4))*KCD + 32 + (tid >> 2))*64
                                     + (b & 15) + (tid & 3)*16)*8;
    uint4 hv = *(const uint4*)hp;
    float hf[8]; unpack8(hv, hf);
    float part = 0.0f;
    #pragma unroll
    for (int j = 0; j < 8; j++) part = fmaf(hf[j], fcW[tid*8 + j], part);
    red[tid] = part; __syncthreads();
    for (int o = 64; o; o >>= 1){
        if (tid < o) red[tid] += red[tid + o];
        __syncthreads();
    }
    if (tid == 0) out[b*Tn + (Tn - 1)] = red[0] + fcb[0];
}

extern "C" void kernel_launch(void* const* d_in, const int* in_sizes, int n_in,
                              void* d_out, int out_size, void* d_ws, size_t ws_size,
                              hipStream_t stream){
    const float* src  = (const float*)d_in[0];
    const float* eWih = (const float*)d_in[1];
    const float* eWhh = (const float*)d_in[2];
    const float* ebih = (const float*)d_in[3];
    const float* ebhh = (const float*)d_in[4];
    const float* dWih = (const float*)d_in[5];
    const float* dWhh = (const float*)d_in[6];
    const float* dbih = (const float*)d_in[7];
    const float* dbhh = (const float*)d_in[8];
    const float* attnW= (const float*)d_in[9];
    const float* fcW  = (const float*)d_in[10];
    const float* fcb  = (const float*)d_in[11];
    float* out = (float*)d_out;

    char* base = (char*)d_ws;
    auto alloc = [&](size_t bytes){ void* p = base; base += (bytes + 255) & ~255ull; return p; };
    unsigned short* Wencf = (unsigned short*)alloc((size_t)256*KCE*512*2);
    float*          benc  = (float*)alloc(G4*4);
    unsigned short* Wdecf = (unsigned short*)alloc((size_t)256*KCD*512*2);
    float*          bdec  = (float*)alloc(G4*4);
    unsigned short* Wattf = (unsigned short*)alloc((size_t)64*KCQ*512*2);
    unsigned short* srcf  = (unsigned short*)alloc((size_t)Sn*8*2*512*2);
    unsigned short* enco  = (unsigned short*)alloc((size_t)Bn*Sn*Hn*2);
    unsigned short* hf0   = (unsigned short*)alloc((size_t)8*32*512*2);
    unsigned short* hf1   = (unsigned short*)alloc((size_t)8*32*512*2);
    float*          cfrag = (float*)alloc((size_t)Bn*Hn*4);
    unsigned short* A0f   = (unsigned short*)alloc((size_t)8*KCD*512*2);
    unsigned short* A1f   = (unsigned short*)alloc((size_t)8*KCD*512*2);
    unsigned short* qbf   = (unsigned short*)alloc((size_t)Bn*Hn*2);

    conv_srcf<<<2048, 256, 0, stream>>>(src, srcf);
    pack_encf<<<4096, 256, 0, stream>>>(eWih, eWhh, ebih, ebhh, Wencf, benc);
    pack_decf<<<8192, 256, 0, stream>>>(dWih, dWhh, dbih, dbhh, Wdecf, bdec);
    pack_attnf<<<1024, 256, 0, stream>>>(attnW, Wattf);
    init_ws<<<1040, 256, 0, stream>>>(hf0, cfrag, A0f, A1f);

    unsigned short* hf[2] = {hf0, hf1};
    unsigned short* Ad[2] = {A0f, A1f};
    dim3 ge(2, 64);

    for (int t = 0; t < Sn; t++){
        enc_step<<<ge, 64, 0, stream>>>(srcf, hf[t&1], Wencf, benc, cfrag,
                                        hf[(t+1)&1], enco, A0f, t, t == Sn-1);
    }
    for (int d = 0; d < Tn; d++){
        unsigned short* Ac = Ad[d&1];
        unsigned short* An = Ad[(d+1)&1];
        attnq_step<<<dim3(4,64), 128, 0, stream>>>(Ac, Wattf, qbf);
        fattn_kernel<<<Bn, 512, 0, stream>>>(qbf, enco, Ac, fcW, fcb, out, d);
        dec_step<<<ge, 64, 0, stream>>>(Ac, Wdecf, bdec, cfrag, An);
    }
    fc_final<<<Bn, 128, 0, stream>>>(Ad[0], fcW, fcb, out);
}

// Round 6
// 11645.349 us; speedup vs baseline: 1.6353x; 1.6353x over previous
//
#include <hip/hip_runtime.h>
#include <math.h>

#define Bn   128
#define Sn   336
#define INd  64
#define Hn   1024
#define Tn   96
#define G4   4096
#define KCE  34     // enc k-chunks: [x(64) | h(1024)]
#define KCD  65     // dec k-chunks: [ctx(1024) | h(1024) | prev_y | pad]
#define KCQ  32     // attn query k-chunks

typedef __attribute__((ext_vector_type(8))) short short8;
typedef __attribute__((ext_vector_type(4))) float floatx4;

__device__ __forceinline__ float sigmoidf_(float x){ return 1.0f/(1.0f+expf(-x)); }

__device__ __forceinline__ unsigned short f2bf(float f){
    union { float f; unsigned u; } v; v.f = f;
    unsigned r = v.u + 0x7fffu + ((v.u >> 16) & 1u);
    return (unsigned short)(r >> 16);
}
__device__ __forceinline__ float bflo(unsigned u){ union{unsigned u; float f;} v; v.u = u << 16;        return v.f; }
__device__ __forceinline__ float bfhi(unsigned u){ union{unsigned u; float f;} v; v.u = u & 0xffff0000u; return v.f; }
__device__ __forceinline__ void unpack8(uint4 v, float* f){
    f[0]=bflo(v.x); f[1]=bfhi(v.x); f[2]=bflo(v.y); f[3]=bfhi(v.y);
    f[4]=bflo(v.z); f[5]=bfhi(v.z); f[6]=bflo(v.w); f[7]=bfhi(v.w);
}

// ===================== fragment-order packing ==============================
// B-fragment subtile s, chunk kc: [s][kc][lane(64)][8];
// lane l: col c=l&15, k = kc*32 + (l>>4)*8 + j. LSTM: gate = s&3, unit = (s>>2)*16+c.
__global__ void pack_encf(const float* __restrict__ Wih, const float* __restrict__ Whh,
                          const float* __restrict__ bih, const float* __restrict__ bhh,
                          unsigned short* __restrict__ Wp, float* __restrict__ bc){
    long n = (long)256*KCE*512;
    for (long idx = (long)blockIdx.x*256 + threadIdx.x; idx < n; idx += (long)gridDim.x*256){
        int j = (int)(idx & 7), l = (int)((idx >> 3) & 63);
        int kc = (int)((idx >> 9) % KCE);
        int s  = (int)(idx / (KCE*512));
        int c = l & 15, kg = l >> 4;
        int k = kc*32 + kg*8 + j;
        int gate = s & 3, unit = (s >> 2)*16 + c;
        int orig = gate*Hn + unit;
        float v = (k < INd) ? Wih[orig*INd + k] : Whh[(size_t)orig*Hn + (k - INd)];
        Wp[idx] = f2bf(v);
    }
    int tid = blockIdx.x*256 + threadIdx.x;
    if (tid < G4){
        int g = (tid >> 4) & 3, u = (tid >> 6)*16 + (tid & 15);
        int orig = g*Hn + u;
        bc[tid] = bih[orig] + bhh[orig];
    }
}

__global__ void pack_decf(const float* __restrict__ Wih, const float* __restrict__ Whh,
                          const float* __restrict__ bih, const float* __restrict__ bhh,
                          unsigned short* __restrict__ Wp, float* __restrict__ bc){
    long n = (long)256*KCD*512;
    for (long idx = (long)blockIdx.x*256 + threadIdx.x; idx < n; idx += (long)gridDim.x*256){
        int j = (int)(idx & 7), l = (int)((idx >> 3) & 63);
        int kc = (int)((idx >> 9) % KCD);
        int s  = (int)(idx / (KCD*512));
        int c = l & 15, kg = l >> 4;
        int k = kc*32 + kg*8 + j;
        int gate = s & 3, unit = (s >> 2)*16 + c;
        int orig = gate*Hn + unit;
        float v;
        if (k < Hn)          v = Wih[(size_t)orig*(Hn+1) + 1 + k];     // ctx
        else if (k < 2*Hn)   v = Whh[(size_t)orig*Hn + (k - Hn)];      // h
        else if (k == 2*Hn)  v = Wih[(size_t)orig*(Hn+1)];             // prev_y
        else                 v = 0.0f;                                  // pad
        Wp[idx] = f2bf(v);
    }
    int tid = blockIdx.x*256 + threadIdx.x;
    if (tid < G4){
        int g = (tid >> 4) & 3, u = (tid >> 6)*16 + (tid & 15);
        int orig = g*Hn + u;
        bc[tid] = bih[orig] + bhh[orig];
    }
}

__global__ void pack_attnf(const float* __restrict__ w, unsigned short* __restrict__ Wp){
    int n = 64*KCQ*512;
    for (int idx = blockIdx.x*256 + threadIdx.x; idx < n; idx += gridDim.x*256){
        int j = idx & 7, l = (idx >> 3) & 63;
        int kc = (idx >> 9) & 31;
        int s  = idx >> 14;
        int nn = s*16 + (l & 15);
        int k = kc*32 + (l >> 4)*8 + j;
        Wp[idx] = f2bf(w[(size_t)nn*Hn + k]);
    }
}

// src A-fragments: [t][rg(8)][kc(2)][lane][8]; row b = rg*16 + (l&15)
__global__ void conv_srcf(const float* __restrict__ s, unsigned short* __restrict__ d){
    int n = Sn*8*2*512;
    for (int idx = blockIdx.x*256 + threadIdx.x; idx < n; idx += gridDim.x*256){
        int j = idx & 7, l = (idx >> 3) & 63;
        int kc = (idx >> 9) & 1, rg = (idx >> 10) & 7, t = idx >> 13;
        int b = rg*16 + (l & 15);
        int k = kc*32 + (l >> 4)*8 + j;
        d[idx] = f2bf(s[((size_t)b*Sn + t)*INd + k]);
    }
}

__global__ void init_ws(unsigned short* __restrict__ hf0, float* __restrict__ cbuf,
                        unsigned short* __restrict__ A0, unsigned short* __restrict__ A1){
    for (int i = blockIdx.x*256 + threadIdx.x; i < 8*KCD*512; i += gridDim.x*256){
        A0[i] = 0; A1[i] = 0;
        if (i < 8*32*512) hf0[i] = 0;
        if (i < Bn*Hn) cbuf[i] = 0.0f;
    }
}

// ===================== encoder step (R4: 256 blocks x 2 waves) =============
__global__ __launch_bounds__(128)
void enc_step(const unsigned short* __restrict__ srcfrag,  // [336][8][2][512]
              const unsigned short* __restrict__ hin,      // [8][32][512]
              const unsigned short* __restrict__ Wf,       // [256][KCE][512]
              const float* __restrict__ bc, float* __restrict__ cbuf,
              unsigned short* __restrict__ hout,           // [8][32][512]
              unsigned short* __restrict__ enco,
              unsigned short* __restrict__ adec0,          // [8][KCD][512]
              int t, int last)
{
    const int tid = threadIdx.x, l = tid & 63, w = tid >> 6;
    const int rg = blockIdx.x*2 + w;
    const int m0 = rg*16;
    const int y = blockIdx.y;
    const unsigned short* Bf = Wf + (size_t)(4*y)*KCE*512 + l*8;
    const unsigned short* Ax = srcfrag + ((size_t)t*8 + rg)*2*512 + l*8;
    const unsigned short* Ah = hin + (size_t)rg*32*512 + l*8;
    floatx4 acc0={0,0,0,0}, acc1={0,0,0,0}, acc2={0,0,0,0}, acc3={0,0,0,0};

    #pragma unroll
    for (int kc = 0; kc < 2; kc++){
        short8 a  = *(const short8*)(Ax + kc*512);
        short8 b0 = *(const short8*)(Bf + (0*KCE + kc)*512);
        short8 b1 = *(const short8*)(Bf + (1*KCE + kc)*512);
        short8 b2 = *(const short8*)(Bf + (2*KCE + kc)*512);
        short8 b3 = *(const short8*)(Bf + (3*KCE + kc)*512);
        acc0 = __builtin_amdgcn_mfma_f32_16x16x32_bf16(a, b0, acc0, 0, 0, 0);
        acc1 = __builtin_amdgcn_mfma_f32_16x16x32_bf16(a, b1, acc1, 0, 0, 0);
        acc2 = __builtin_amdgcn_mfma_f32_16x16x32_bf16(a, b2, acc2, 0, 0, 0);
        acc3 = __builtin_amdgcn_mfma_f32_16x16x32_bf16(a, b3, acc3, 0, 0, 0);
    }
    #pragma unroll 4
    for (int kc = 0; kc < 32; kc++){
        short8 a  = *(const short8*)(Ah + kc*512);
        short8 b0 = *(const short8*)(Bf + (0*KCE + kc + 2)*512);
        short8 b1 = *(const short8*)(Bf + (1*KCE + kc + 2)*512);
        short8 b2 = *(const short8*)(Bf + (2*KCE + kc + 2)*512);
        short8 b3 = *(const short8*)(Bf + (3*KCE + kc + 2)*512);
        acc0 = __builtin_amdgcn_mfma_f32_16x16x32_bf16(a, b0, acc0, 0, 0, 0);
        acc1 = __builtin_amdgcn_mfma_f32_16x16x32_bf16(a, b1, acc1, 0, 0, 0);
        acc2 = __builtin_amdgcn_mfma_f32_16x16x32_bf16(a, b2, acc2, 0, 0, 0);
        acc3 = __builtin_amdgcn_mfma_f32_16x16x32_bf16(a, b3, acc3, 0, 0, 0);
    }

    const int col = l & 15, q = l >> 4;
    const int u = y*16 + col;
    const float bi  = bc[y*64 + col];
    const float bf_ = bc[y*64 + 16 + col];
    const float bg  = bc[y*64 + 32 + col];
    const float bo  = bc[y*64 + 48 + col];
    const int lsh = ((u >> 3) & 3) * 16;
    #pragma unroll
    for (int r = 0; r < 4; r++){
        const int m = m0 + q*4 + r;
        float gi = acc0[r] + bi;
        float gf = acc1[r] + bf_;
        float gg = acc2[r] + bg;
        float go = acc3[r] + bo;
        float co = cbuf[(size_t)m*Hn + u];
        float cn = sigmoidf_(gf)*co + sigmoidf_(gi)*tanhf(gg);
        float hv = sigmoidf_(go)*tanhf(cn);
        cbuf[(size_t)m*Hn + u] = cn;
        unsigned short hb = f2bf(hv);
        const int lanep = (q*4 + r) + lsh;
        hout[(((size_t)rg*32 + (u >> 5))*64 + lanep)*8 + (u & 7)] = hb;
        enco[((size_t)m*Sn + t)*Hn + u] = hb;
        if (last) adec0[(((size_t)rg*KCD + 32 + (u >> 5))*64 + lanep)*8 + (u & 7)] = hb;
    }
}

// ===================== decoder LSTM step (R4 minus hrow) ===================
__global__ __launch_bounds__(128)
void dec_step(const unsigned short* __restrict__ Ac,       // [8][KCD][512]
              const unsigned short* __restrict__ Wf,       // [256][KCD][512]
              const float* __restrict__ bc, float* __restrict__ cbuf,
              unsigned short* __restrict__ An)              // next A h-slot
{
    const int tid = threadIdx.x, l = tid & 63, w = tid >> 6;
    const int rg = blockIdx.x*2 + w;
    const int m0 = rg*16;
    const int y = blockIdx.y;
    const unsigned short* Bf = Wf + (size_t)(4*y)*KCD*512 + l*8;
    const unsigned short* Af = Ac + (size_t)rg*KCD*512 + l*8;
    floatx4 acc0={0,0,0,0}, acc1={0,0,0,0}, acc2={0,0,0,0}, acc3={0,0,0,0};

    #pragma unroll 4
    for (int kc = 0; kc < KCD; kc++){
        short8 a  = *(const short8*)(Af + kc*512);
        short8 b0 = *(const short8*)(Bf + (0*KCD + kc)*512);
        short8 b1 = *(const short8*)(Bf + (1*KCD + kc)*512);
        short8 b2 = *(const short8*)(Bf + (2*KCD + kc)*512);
        short8 b3 = *(const short8*)(Bf + (3*KCD + kc)*512);
        acc0 = __builtin_amdgcn_mfma_f32_16x16x32_bf16(a, b0, acc0, 0, 0, 0);
        acc1 = __builtin_amdgcn_mfma_f32_16x16x32_bf16(a, b1, acc1, 0, 0, 0);
        acc2 = __builtin_amdgcn_mfma_f32_16x16x32_bf16(a, b2, acc2, 0, 0, 0);
        acc3 = __builtin_amdgcn_mfma_f32_16x16x32_bf16(a, b3, acc3, 0, 0, 0);
    }

    const int col = l & 15, q = l >> 4;
    const int u = y*16 + col;
    const float bi  = bc[y*64 + col];
    const float bf_ = bc[y*64 + 16 + col];
    const float bg  = bc[y*64 + 32 + col];
    const float bo  = bc[y*64 + 48 + col];
    const int lsh = ((u >> 3) & 3) * 16;
    #pragma unroll
    for (int r = 0; r < 4; r++){
        const int m = m0 + q*4 + r;
        float gi = acc0[r] + bi;
        float gf = acc1[r] + bf_;
        float gg = acc2[r] + bg;
        float go = acc3[r] + bo;
        float co = cbuf[(size_t)m*Hn + u];
        float cn = sigmoidf_(gf)*co + sigmoidf_(gi)*tanhf(gg);
        float hv = sigmoidf_(go)*tanhf(cn);
        cbuf[(size_t)m*Hn + u] = cn;
        const int lanep = (q*4 + r) + lsh;
        An[(((size_t)rg*KCD + 32 + (u >> 5))*64 + lanep)*8 + (u & 7)] = f2bf(hv);
    }
}

// ===================== attention query GEMM ================================
__global__ __launch_bounds__(128)
void attnq_step(const unsigned short* __restrict__ Ac, const unsigned short* __restrict__ Wf,
                unsigned short* __restrict__ qout)
{
    const int tid = threadIdx.x, l = tid & 63, w = tid >> 6;
    const int rg = blockIdx.x*2 + w;
    const int m0 = rg*16;
    const int y = blockIdx.y;
    const unsigned short* Bf = Wf + (size_t)y*KCQ*512 + l*8;
    const unsigned short* Af = Ac + ((size_t)rg*KCD + 32)*512 + l*8;
    floatx4 acc = {0,0,0,0};
    #pragma unroll 8
    for (int kc = 0; kc < KCQ; kc++){
        short8 a = *(const short8*)(Af + kc*512);
        short8 b = *(const short8*)(Bf + kc*512);
        acc = __builtin_amdgcn_mfma_f32_16x16x32_bf16(a, b, acc, 0, 0, 0);
    }
    const int col = l & 15, q = l >> 4;
    #pragma unroll
    for (int r = 0; r < 4; r++){
        const int m = m0 + q*4 + r;
        qout[(size_t)m*Hn + y*16 + col] = f2bf(acc[r]);
    }
}

// ===================== fused attention: online softmax + ctx + fc ==========
// block per b, 512 thr = 8 waves; wave w handles s = w, w+8, ...
// Also computes fc(prev h) -> out[d-1] + prev_y slot (d>0).
__global__ __launch_bounds__(512)
void fattn_kernel(const unsigned short* __restrict__ q,    // [128][1024]
                  const unsigned short* __restrict__ enc,  // [128][336][1024]
                  unsigned short* __restrict__ Ac,         // fragment A buffer
                  const float* __restrict__ fcW, const float* __restrict__ fcb,
                  float* __restrict__ out, int d)
{
    __shared__ float ctxl[8*1024];
    __shared__ float mred[8], lred[8];
    __shared__ float fcred[128];
    const int b = blockIdx.x;
    const int tid = threadIdx.x, w = tid >> 6, l = tid & 63;

    float qv[16];
    {
        const uint4* qp = (const uint4*)(q + (size_t)b*Hn) + l*2;
        uint4 q0 = qp[0], q1 = qp[1];
        unpack8(q0, qv); unpack8(q1, qv + 8);
    }
    float m = -1e30f, lsum = 0.0f;
    float cacc[16];
    #pragma unroll
    for (int i = 0; i < 16; i++) cacc[i] = 0.0f;

    const uint4* ebase = (const uint4*)(enc + (size_t)b*Sn*Hn) + l*2;
    for (int s = w; s < Sn; s += 8){
        uint4 e0 = ebase[(size_t)s*128];
        uint4 e1 = ebase[(size_t)s*128 + 1];
        float ev[16];
        unpack8(e0, ev); unpack8(e1, ev + 8);
        float part = 0.0f;
        #pragma unroll
        for (int i = 0; i < 16; i++) part = fmaf(qv[i], ev[i], part);
        #pragma unroll
        for (int off = 32; off; off >>= 1) part += __shfl_down(part, off);
        float e = __shfl(part, 0);
        float mn = fmaxf(m, e);
        float corr = expf(m - mn);
        float p = expf(e - mn);
        lsum = lsum*corr + p;
        if (corr != 1.0f){
            #pragma unroll
            for (int i = 0; i < 16; i++) cacc[i] *= corr;
        }
        #pragma unroll
        for (int i = 0; i < 16; i++) cacc[i] = fmaf(p, ev[i], cacc[i]);
        m = mn;
    }
    if (l == 0){ mred[w] = m; lred[w] = lsum; }
    __syncthreads();
    float M = mred[0];
    #pragma unroll
    for (int k = 1; k < 8; k++) M = fmaxf(M, mred[k]);
    float corr = expf(m - M);
    // transposed store: element l*16+j at [w*1024 + j*64 + l] (conflict-free)
    #pragma unroll
    for (int j = 0; j < 16; j++) ctxl[w*1024 + j*64 + l] = cacc[j]*corr;
    __syncthreads();
    float L = 0.0f;
    #pragma unroll
    for (int k = 0; k < 8; k++) L += lred[k]*expf(mred[k] - M);
    float invL = 1.0f / L;

    // each thread: elements 2*tid, 2*tid+1 -> ctx fragment store (4B)
    {
        const int u0 = 2*tid;
        float s0 = 0.0f, s1 = 0.0f;
        #pragma unroll
        for (int k = 0; k < 8; k++){
            s0 += ctxl[k*1024 + (u0 & 15)*64 + (u0 >> 4)];
            s1 += ctxl[k*1024 + ((u0+1) & 15)*64 + ((u0+1) >> 4)];
        }
        ushort2 cv; cv.x = f2bf(s0*invL); cv.y = f2bf(s1*invL);
        const int kc = u0 >> 5;
        const int lanep = (b & 15) + ((u0 >> 3) & 3)*16;
        *(ushort2*)(Ac + ((((size_t)(b >> 4))*KCD + kc)*64 + lanep)*8 + (u0 & 7)) = cv;
    }

    // fc of h currently in Ac h-slot (result of previous dec_step)
    float part = 0.0f;
    if (tid < 128){
        const unsigned short* hp = Ac + ((((size_t)(b >> 4))*KCD + 32 + (tid >> 2))*64
                                         + (b & 15) + (tid & 3)*16)*8;
        uint4 hv = *(const uint4*)hp;
        float hf[8]; unpack8(hv, hf);
        #pragma unroll
        for (int j = 0; j < 8; j++) part = fmaf(hf[j], fcW[tid*8 + j], part);
    }
    __syncthreads();
    if (tid < 128) fcred[tid] = part;
    __syncthreads();
    for (int o = 64; o; o >>= 1){
        if (tid < o && tid + o < 128) fcred[tid] += fcred[tid + o];
        __syncthreads();
    }
    if (tid == 0 && d > 0){
        float p = fcred[0] + fcb[0];
        out[b*Tn + (d - 1)] = p;
        Ac[(((size_t)(b >> 4))*KCD + 64)*512 + (b & 15)*8] = f2bf(p);
    }
}

// ===================== final fc ============================================
__global__ __launch_bounds__(128)
void fc_final(const unsigned short* __restrict__ A, const float* __restrict__ fcW,
              const float* __restrict__ fcb, float* __restrict__ out){
    __shared__ float red[128];
    const int b = blockIdx.x, tid = threadIdx.x;
    const unsigned short* hp = A + ((((size_t)(b >> 4))*KCD + 32 + (tid >> 2))*64
                                     + (b & 15) + (tid & 3)*16)*8;
    uint4 hv = *(const uint4*)hp;
    float hf[8]; unpack8(hv, hf);
    float part = 0.0f;
    #pragma unroll
    for (int j = 0; j < 8; j++) part = fmaf(hf[j], fcW[tid*8 + j], part);
    red[tid] = part; __syncthreads();
    for (int o = 64; o; o >>= 1){
        if (tid < o) red[tid] += red[tid + o];
        __syncthreads();
    }
    if (tid == 0) out[b*Tn + (Tn - 1)] = red[0] + fcb[0];
}

extern "C" void kernel_launch(void* const* d_in, const int* in_sizes, int n_in,
                              void* d_out, int out_size, void* d_ws, size_t ws_size,
                              hipStream_t stream){
    const float* src  = (const float*)d_in[0];
    const float* eWih = (const float*)d_in[1];
    const float* eWhh = (const float*)d_in[2];
    const float* ebih = (const float*)d_in[3];
    const float* ebhh = (const float*)d_in[4];
    const float* dWih = (const float*)d_in[5];
    const float* dWhh = (const float*)d_in[6];
    const float* dbih = (const float*)d_in[7];
    const float* dbhh = (const float*)d_in[8];
    const float* attnW= (const float*)d_in[9];
    const float* fcW  = (const float*)d_in[10];
    const float* fcb  = (const float*)d_in[11];
    float* out = (float*)d_out;

    char* base = (char*)d_ws;
    auto alloc = [&](size_t bytes){ void* p = base; base += (bytes + 255) & ~255ull; return p; };
    unsigned short* Wencf = (unsigned short*)alloc((size_t)256*KCE*512*2);
    float*          benc  = (float*)alloc(G4*4);
    unsigned short* Wdecf = (unsigned short*)alloc((size_t)256*KCD*512*2);
    float*          bdec  = (float*)alloc(G4*4);
    unsigned short* Wattf = (unsigned short*)alloc((size_t)64*KCQ*512*2);
    unsigned short* srcf  = (unsigned short*)alloc((size_t)Sn*8*2*512*2);
    unsigned short* enco  = (unsigned short*)alloc((size_t)Bn*Sn*Hn*2);
    unsigned short* hf0   = (unsigned short*)alloc((size_t)8*32*512*2);
    unsigned short* hf1   = (unsigned short*)alloc((size_t)8*32*512*2);
    float*          cbuf  = (float*)alloc((size_t)Bn*Hn*4);
    unsigned short* A0f   = (unsigned short*)alloc((size_t)8*KCD*512*2);
    unsigned short* A1f   = (unsigned short*)alloc((size_t)8*KCD*512*2);
    unsigned short* qbf   = (unsigned short*)alloc((size_t)Bn*Hn*2);

    conv_srcf<<<2048, 256, 0, stream>>>(src, srcf);
    pack_encf<<<4096, 256, 0, stream>>>(eWih, eWhh, ebih, ebhh, Wencf, benc);
    pack_decf<<<8192, 256, 0, stream>>>(dWih, dWhh, dbih, dbhh, Wdecf, bdec);
    pack_attnf<<<1024, 256, 0, stream>>>(attnW, Wattf);
    init_ws<<<1040, 256, 0, stream>>>(hf0, cbuf, A0f, A1f);

    unsigned short* hf[2] = {hf0, hf1};
    unsigned short* Ad[2] = {A0f, A1f};
    dim3 gg(4, 64);

    for (int t = 0; t < Sn; t++){
        enc_step<<<gg, 128, 0, stream>>>(srcf, hf[t&1], Wencf, benc, cbuf,
                                         hf[(t+1)&1], enco, A0f, t, t == Sn-1);
    }
    for (int d = 0; d < Tn; d++){
        unsigned short* Ac = Ad[d&1];
        unsigned short* An = Ad[(d+1)&1];
        attnq_step<<<dim3(4,64), 128, 0, stream>>>(Ac, Wattf, qbf);
        fattn_kernel<<<Bn, 512, 0, stream>>>(qbf, enco, Ac, fcW, fcb, out, d);
        dec_step<<<gg, 128, 0, stream>>>(Ac, Wdecf, bdec, cbuf, An);
    }
    fc_final<<<Bn, 128, 0, stream>>>(Ad[0], fcW, fcb, out);
}

// Round 8
// 9941.211 us; speedup vs baseline: 1.9156x; 1.1714x over previous
//
#include <hip/hip_runtime.h>
#include <math.h>

#define Bn   128
#define Sn   336
#define INd  64
#define Hn   1024
#define Tn   96
#define G4   4096
#define KCE  34     // enc k-chunks: [x(64) | h(1024)]
#define KCD  65     // dec k-chunks: [ctx(1024) | h(1024) | prev_y | pad]
#define KCQ  32     // attn query k-chunks

typedef __attribute__((ext_vector_type(8))) short short8;
typedef __attribute__((ext_vector_type(4))) float floatx4;
typedef __attribute__((ext_vector_type(4))) unsigned int uintx4;

__device__ __forceinline__ float sigmoidf_(float x){ return 1.0f/(1.0f+expf(-x)); }

__device__ __forceinline__ unsigned short f2bf(float f){
    union { float f; unsigned u; } v; v.f = f;
    unsigned r = v.u + 0x7fffu + ((v.u >> 16) & 1u);
    return (unsigned short)(r >> 16);
}
__device__ __forceinline__ float bflo(unsigned u){ union{unsigned u; float f;} v; v.u = u << 16;        return v.f; }
__device__ __forceinline__ float bfhi(unsigned u){ union{unsigned u; float f;} v; v.u = u & 0xffff0000u; return v.f; }
__device__ __forceinline__ void unpack8v(uintx4 v, float* f){
    f[0]=bflo(v.x); f[1]=bfhi(v.x); f[2]=bflo(v.y); f[3]=bfhi(v.y);
    f[4]=bflo(v.z); f[5]=bfhi(v.z); f[6]=bflo(v.w); f[7]=bfhi(v.w);
}

// ===================== fragment-order packing ==============================
// B-fragment subtile s, chunk kc: [s][kc][lane(64)][8];
// lane l: col c=l&15, k = kc*32 + (l>>4)*8 + j. LSTM: gate = s&3, unit = (s>>2)*16+c.
__global__ void pack_encf(const float* __restrict__ Wih, const float* __restrict__ Whh,
                          const float* __restrict__ bih, const float* __restrict__ bhh,
                          unsigned short* __restrict__ Wp, float* __restrict__ bc){
    long n = (long)256*KCE*512;
    for (long idx = (long)blockIdx.x*256 + threadIdx.x; idx < n; idx += (long)gridDim.x*256){
        int j = (int)(idx & 7), l = (int)((idx >> 3) & 63);
        int kc = (int)((idx >> 9) % KCE);
        int s  = (int)(idx / (KCE*512));
        int c = l & 15, kg = l >> 4;
        int k = kc*32 + kg*8 + j;
        int gate = s & 3, unit = (s >> 2)*16 + c;
        int orig = gate*Hn + unit;
        float v = (k < INd) ? Wih[orig*INd + k] : Whh[(size_t)orig*Hn + (k - INd)];
        Wp[idx] = f2bf(v);
    }
    int tid = blockIdx.x*256 + threadIdx.x;
    if (tid < G4){
        int g = (tid >> 4) & 3, u = (tid >> 6)*16 + (tid & 15);
        int orig = g*Hn + u;
        bc[tid] = bih[orig] + bhh[orig];
    }
}

__global__ void pack_decf(const float* __restrict__ Wih, const float* __restrict__ Whh,
                          const float* __restrict__ bih, const float* __restrict__ bhh,
                          unsigned short* __restrict__ Wp, float* __restrict__ bc){
    long n = (long)256*KCD*512;
    for (long idx = (long)blockIdx.x*256 + threadIdx.x; idx < n; idx += (long)gridDim.x*256){
        int j = (int)(idx & 7), l = (int)((idx >> 3) & 63);
        int kc = (int)((idx >> 9) % KCD);
        int s  = (int)(idx / (KCD*512));
        int c = l & 15, kg = l >> 4;
        int k = kc*32 + kg*8 + j;
        int gate = s & 3, unit = (s >> 2)*16 + c;
        int orig = gate*Hn + unit;
        float v;
        if (k < Hn)          v = Wih[(size_t)orig*(Hn+1) + 1 + k];     // ctx
        else if (k < 2*Hn)   v = Whh[(size_t)orig*Hn + (k - Hn)];      // h
        else if (k == 2*Hn)  v = Wih[(size_t)orig*(Hn+1)];             // prev_y
        else                 v = 0.0f;                                  // pad
        Wp[idx] = f2bf(v);
    }
    int tid = blockIdx.x*256 + threadIdx.x;
    if (tid < G4){
        int g = (tid >> 4) & 3, u = (tid >> 6)*16 + (tid & 15);
        int orig = g*Hn + u;
        bc[tid] = bih[orig] + bhh[orig];
    }
}

__global__ void pack_attnf(const float* __restrict__ w, unsigned short* __restrict__ Wp){
    int n = 64*KCQ*512;
    for (int idx = blockIdx.x*256 + threadIdx.x; idx < n; idx += gridDim.x*256){
        int j = idx & 7, l = (idx >> 3) & 63;
        int kc = (idx >> 9) & 31;
        int s  = idx >> 14;
        int nn = s*16 + (l & 15);
        int k = kc*32 + (l >> 4)*8 + j;
        Wp[idx] = f2bf(w[(size_t)nn*Hn + k]);
    }
}

// src A-fragments: [t][rg(8)][kc(2)][lane][8]; row b = rg*16 + (l&15)
__global__ void conv_srcf(const float* __restrict__ s, unsigned short* __restrict__ d){
    int n = Sn*8*2*512;
    for (int idx = blockIdx.x*256 + threadIdx.x; idx < n; idx += gridDim.x*256){
        int j = idx & 7, l = (idx >> 3) & 63;
        int kc = (idx >> 9) & 1, rg = (idx >> 10) & 7, t = idx >> 13;
        int b = rg*16 + (l & 15);
        int k = kc*32 + (l >> 4)*8 + j;
        d[idx] = f2bf(s[((size_t)b*Sn + t)*INd + k]);
    }
}

__global__ void init_ws(unsigned short* __restrict__ hf0, float* __restrict__ cbuf,
                        unsigned short* __restrict__ A0, unsigned short* __restrict__ A1){
    for (int i = blockIdx.x*256 + threadIdx.x; i < 8*KCD*512; i += gridDim.x*256){
        A0[i] = 0; A1[i] = 0;
        if (i < 8*32*512) hf0[i] = 0;
        if (i < Bn*Hn) cbuf[i] = 0.0f;
    }
}

// XCD-aware swizzle for 256-block step kernels: blocks on XCD k (assuming
// round-robin linear-id -> XCD) own y in [k*8, k*8+8) -> per-XCD weight slice
// is L2-resident across all recurrence steps.
__device__ __forceinline__ void swz(int b, int& x, int& y){
    int xcd = b & 7, li = b >> 3;
    y = xcd*8 + (li & 7);
    x = li >> 3;
}

// ===================== encoder step ========================================
__global__ __launch_bounds__(128)
void enc_step(const unsigned short* __restrict__ srcfrag,  // [336][8][2][512]
              const unsigned short* __restrict__ hin,      // [8][32][512]
              const unsigned short* __restrict__ Wf,       // [256][KCE][512]
              const float* __restrict__ bc, float* __restrict__ cbuf,
              unsigned short* __restrict__ hout,           // [8][32][512]
              unsigned short* __restrict__ enco,
              unsigned short* __restrict__ adec0,          // [8][KCD][512]
              int t, int last)
{
    const int tid = threadIdx.x, l = tid & 63, w = tid >> 6;
    int x, y; swz(blockIdx.x, x, y);
    const int rg = x*2 + w;
    const int m0 = rg*16;
    const unsigned short* Bf = Wf + (size_t)(4*y)*KCE*512 + l*8;
    const unsigned short* Ax = srcfrag + ((size_t)t*8 + rg)*2*512 + l*8;
    const unsigned short* Ah = hin + (size_t)rg*32*512 + l*8;
    floatx4 acc0={0,0,0,0}, acc1={0,0,0,0}, acc2={0,0,0,0}, acc3={0,0,0,0};

    #pragma unroll
    for (int kc = 0; kc < 2; kc++){
        short8 a  = *(const short8*)(Ax + kc*512);
        short8 b0 = *(const short8*)(Bf + (0*KCE + kc)*512);
        short8 b1 = *(const short8*)(Bf + (1*KCE + kc)*512);
        short8 b2 = *(const short8*)(Bf + (2*KCE + kc)*512);
        short8 b3 = *(const short8*)(Bf + (3*KCE + kc)*512);
        acc0 = __builtin_amdgcn_mfma_f32_16x16x32_bf16(a, b0, acc0, 0, 0, 0);
        acc1 = __builtin_amdgcn_mfma_f32_16x16x32_bf16(a, b1, acc1, 0, 0, 0);
        acc2 = __builtin_amdgcn_mfma_f32_16x16x32_bf16(a, b2, acc2, 0, 0, 0);
        acc3 = __builtin_amdgcn_mfma_f32_16x16x32_bf16(a, b3, acc3, 0, 0, 0);
    }
    #pragma unroll 4
    for (int kc = 0; kc < 32; kc++){
        short8 a  = *(const short8*)(Ah + kc*512);
        short8 b0 = *(const short8*)(Bf + (0*KCE + kc + 2)*512);
        short8 b1 = *(const short8*)(Bf + (1*KCE + kc + 2)*512);
        short8 b2 = *(const short8*)(Bf + (2*KCE + kc + 2)*512);
        short8 b3 = *(const short8*)(Bf + (3*KCE + kc + 2)*512);
        acc0 = __builtin_amdgcn_mfma_f32_16x16x32_bf16(a, b0, acc0, 0, 0, 0);
        acc1 = __builtin_amdgcn_mfma_f32_16x16x32_bf16(a, b1, acc1, 0, 0, 0);
        acc2 = __builtin_amdgcn_mfma_f32_16x16x32_bf16(a, b2, acc2, 0, 0, 0);
        acc3 = __builtin_amdgcn_mfma_f32_16x16x32_bf16(a, b3, acc3, 0, 0, 0);
    }

    const int col = l & 15, q = l >> 4;
    const int u = y*16 + col;
    const float bi  = bc[y*64 + col];
    const float bf_ = bc[y*64 + 16 + col];
    const float bg  = bc[y*64 + 32 + col];
    const float bo  = bc[y*64 + 48 + col];
    const int lsh = ((u >> 3) & 3) * 16;
    #pragma unroll
    for (int r = 0; r < 4; r++){
        const int m = m0 + q*4 + r;
        float gi = acc0[r] + bi;
        float gf = acc1[r] + bf_;
        float gg = acc2[r] + bg;
        float go = acc3[r] + bo;
        float co = cbuf[(size_t)m*Hn + u];
        float cn = sigmoidf_(gf)*co + sigmoidf_(gi)*tanhf(gg);
        float hv = sigmoidf_(go)*tanhf(cn);
        cbuf[(size_t)m*Hn + u] = cn;
        unsigned short hb = f2bf(hv);
        const int lanep = (q*4 + r) + lsh;
        hout[(((size_t)rg*32 + (u >> 5))*64 + lanep)*8 + (u & 7)] = hb;
        __builtin_nontemporal_store(hb, enco + ((size_t)m*Sn + t)*Hn + u);
        if (last) adec0[(((size_t)rg*KCD + 32 + (u >> 5))*64 + lanep)*8 + (u & 7)] = hb;
    }
}

// ===================== decoder LSTM step ===================================
__global__ __launch_bounds__(128)
void dec_step(const unsigned short* __restrict__ Ac,       // [8][KCD][512]
              const unsigned short* __restrict__ Wf,       // [256][KCD][512]
              const float* __restrict__ bc, float* __restrict__ cbuf,
              unsigned short* __restrict__ An)              // next A h-slot
{
    const int tid = threadIdx.x, l = tid & 63, w = tid >> 6;
    int x, y; swz(blockIdx.x, x, y);
    const int rg = x*2 + w;
    const int m0 = rg*16;
    const unsigned short* Bf = Wf + (size_t)(4*y)*KCD*512 + l*8;
    const unsigned short* Af = Ac + (size_t)rg*KCD*512 + l*8;
    floatx4 acc0={0,0,0,0}, acc1={0,0,0,0}, acc2={0,0,0,0}, acc3={0,0,0,0};

    #pragma unroll 4
    for (int kc = 0; kc < KCD; kc++){
        short8 a  = *(const short8*)(Af + kc*512);
        short8 b0 = *(const short8*)(Bf + (0*KCD + kc)*512);
        short8 b1 = *(const short8*)(Bf + (1*KCD + kc)*512);
        short8 b2 = *(const short8*)(Bf + (2*KCD + kc)*512);
        short8 b3 = *(const short8*)(Bf + (3*KCD + kc)*512);
        acc0 = __builtin_amdgcn_mfma_f32_16x16x32_bf16(a, b0, acc0, 0, 0, 0);
        acc1 = __builtin_amdgcn_mfma_f32_16x16x32_bf16(a, b1, acc1, 0, 0, 0);
        acc2 = __builtin_amdgcn_mfma_f32_16x16x32_bf16(a, b2, acc2, 0, 0, 0);
        acc3 = __builtin_amdgcn_mfma_f32_16x16x32_bf16(a, b3, acc3, 0, 0, 0);
    }

    const int col = l & 15, q = l >> 4;
    const int u = y*16 + col;
    const float bi  = bc[y*64 + col];
    const float bf_ = bc[y*64 + 16 + col];
    const float bg  = bc[y*64 + 32 + col];
    const float bo  = bc[y*64 + 48 + col];
    const int lsh = ((u >> 3) & 3) * 16;
    #pragma unroll
    for (int r = 0; r < 4; r++){
        const int m = m0 + q*4 + r;
        float gi = acc0[r] + bi;
        float gf = acc1[r] + bf_;
        float gg = acc2[r] + bg;
        float go = acc3[r] + bo;
        float co = cbuf[(size_t)m*Hn + u];
        float cn = sigmoidf_(gf)*co + sigmoidf_(gi)*tanhf(gg);
        float hv = sigmoidf_(go)*tanhf(cn);
        cbuf[(size_t)m*Hn + u] = cn;
        const int lanep = (q*4 + r) + lsh;
        An[(((size_t)rg*KCD + 32 + (u >> 5))*64 + lanep)*8 + (u & 7)] = f2bf(hv);
    }
}

// ===================== attention query GEMM ================================
__global__ __launch_bounds__(128)
void attnq_step(const unsigned short* __restrict__ Ac, const unsigned short* __restrict__ Wf,
                unsigned short* __restrict__ qout)
{
    const int tid = threadIdx.x, l = tid & 63, w = tid >> 6;
    int x, y; swz(blockIdx.x, x, y);
    const int rg = x*2 + w;
    const int m0 = rg*16;
    const unsigned short* Bf = Wf + (size_t)y*KCQ*512 + l*8;
    const unsigned short* Af = Ac + ((size_t)rg*KCD + 32)*512 + l*8;
    floatx4 acc = {0,0,0,0};
    #pragma unroll 8
    for (int kc = 0; kc < KCQ; kc++){
        short8 a = *(const short8*)(Af + kc*512);
        short8 b = *(const short8*)(Bf + kc*512);
        acc = __builtin_amdgcn_mfma_f32_16x16x32_bf16(a, b, acc, 0, 0, 0);
    }
    const int col = l & 15, q = l >> 4;
    #pragma unroll
    for (int r = 0; r < 4; r++){
        const int m = m0 + q*4 + r;
        qout[(size_t)m*Hn + y*16 + col] = f2bf(acc[r]);
    }
}

// ===================== fused attention: online softmax + ctx + fc ==========
// block per b, 512 thr = 8 waves; wave w handles s = w, w+8, ...
// enco loads are NONTEMPORAL so the 88 MB stream doesn't evict L2-resident
// decoder weights between dec_steps.
__global__ __launch_bounds__(512)
void fattn_kernel(const unsigned short* __restrict__ q,    // [128][1024]
                  const unsigned short* __restrict__ enc,  // [128][336][1024]
                  unsigned short* __restrict__ Ac,         // fragment A buffer
                  const float* __restrict__ fcW, const float* __restrict__ fcb,
                  float* __restrict__ out, int d)
{
    __shared__ float ctxl[8*1024];
    __shared__ float mred[8], lred[8];
    __shared__ float fcred[128];
    const int b = blockIdx.x;
    const int tid = threadIdx.x, w = tid >> 6, l = tid & 63;

    float qv[16];
    {
        const uintx4* qp = (const uintx4*)(q + (size_t)b*Hn) + l*2;
        uintx4 q0 = qp[0], q1 = qp[1];
        unpack8v(q0, qv); unpack8v(q1, qv + 8);
    }
    float m = -1e30f, lsum = 0.0f;
    float cacc[16];
    #pragma unroll
    for (int i = 0; i < 16; i++) cacc[i] = 0.0f;

    const uintx4* ebase = (const uintx4*)(enc + (size_t)b*Sn*Hn) + l*2;
    for (int s = w; s < Sn; s += 8){
        uintx4 e0 = __builtin_nontemporal_load(ebase + (size_t)s*128);
        uintx4 e1 = __builtin_nontemporal_load(ebase + (size_t)s*128 + 1);
        float ev[16];
        unpack8v(e0, ev); unpack8v(e1, ev + 8);
        float part = 0.0f;
        #pragma unroll
        for (int i = 0; i < 16; i++) part = fmaf(qv[i], ev[i], part);
        #pragma unroll
        for (int off = 32; off; off >>= 1) part += __shfl_down(part, off);
        float e = __shfl(part, 0);
        float mn = fmaxf(m, e);
        float corr = expf(m - mn);
        float p = expf(e - mn);
        lsum = lsum*corr + p;
        if (corr != 1.0f){
            #pragma unroll
            for (int i = 0; i < 16; i++) cacc[i] *= corr;
        }
        #pragma unroll
        for (int i = 0; i < 16; i++) cacc[i] = fmaf(p, ev[i], cacc[i]);
        m = mn;
    }
    if (l == 0){ mred[w] = m; lred[w] = lsum; }
    __syncthreads();
    float M = mred[0];
    #pragma unroll
    for (int k = 1; k < 8; k++) M = fmaxf(M, mred[k]);
    float corr = expf(m - M);
    #pragma unroll
    for (int j = 0; j < 16; j++) ctxl[w*1024 + j*64 + l] = cacc[j]*corr;
    __syncthreads();
    float L = 0.0f;
    #pragma unroll
    for (int k = 0; k < 8; k++) L += lred[k]*expf(mred[k] - M);
    float invL = 1.0f / L;

    {
        const int u0 = 2*tid;
        float s0 = 0.0f, s1 = 0.0f;
        #pragma unroll
        for (int k = 0; k < 8; k++){
            s0 += ctxl[k*1024 + (u0 & 15)*64 + (u0 >> 4)];
            s1 += ctxl[k*1024 + ((u0+1) & 15)*64 + ((u0+1) >> 4)];
        }
        ushort2 cv; cv.x = f2bf(s0*invL); cv.y = f2bf(s1*invL);
        const int kc = u0 >> 5;
        const int lanep = (b & 15) + ((u0 >> 3) & 3)*16;
        *(ushort2*)(Ac + ((((size_t)(b >> 4))*KCD + kc)*64 + lanep)*8 + (u0 & 7)) = cv;
    }

    float part = 0.0f;
    if (tid < 128){
        const unsigned short* hp = Ac + ((((size_t)(b >> 4))*KCD + 32 + (tid >> 2))*64
                                         + (b & 15) + (tid & 3)*16)*8;
        uintx4 hv = *(const uintx4*)hp;
        float hf[8]; unpack8v(hv, hf);
        #pragma unroll
        for (int j = 0; j < 8; j++) part = fmaf(hf[j], fcW[tid*8 + j], part);
    }
    __syncthreads();
    if (tid < 128) fcred[tid] = part;
    __syncthreads();
    for (int o = 64; o; o >>= 1){
        if (tid < o && tid + o < 128) fcred[tid] += fcred[tid + o];
        __syncthreads();
    }
    if (tid == 0 && d > 0){
        float p = fcred[0] + fcb[0];
        out[b*Tn + (d - 1)] = p;
        Ac[(((size_t)(b >> 4))*KCD + 64)*512 + (b & 15)*8] = f2bf(p);
    }
}

// ===================== final fc ============================================
__global__ __launch_bounds__(128)
void fc_final(const unsigned short* __restrict__ A, const float* __restrict__ fcW,
              const float* __restrict__ fcb, float* __restrict__ out){
    __shared__ float red[128];
    const int b = blockIdx.x, tid = threadIdx.x;
    const unsigned short* hp = A + ((((size_t)(b >> 4))*KCD + 32 + (tid >> 2))*64
                                     + (b & 15) + (tid & 3)*16)*8;
    uintx4 hv = *(const uintx4*)hp;
    float hf[8]; unpack8v(hv, hf);
    float part = 0.0f;
    #pragma unroll
    for (int j = 0; j < 8; j++) part = fmaf(hf[j], fcW[tid*8 + j], part);
    red[tid] = part; __syncthreads();
    for (int o = 64; o; o >>= 1){
        if (tid < o) red[tid] += red[tid + o];
        __syncthreads();
    }
    if (tid == 0) out[b*Tn + (Tn - 1)] = red[0] + fcb[0];
}

extern "C" void kernel_launch(void* const* d_in, const int* in_sizes, int n_in,
                              void* d_out, int out_size, void* d_ws, size_t ws_size,
                              hipStream_t stream){
    const float* src  = (const float*)d_in[0];
    const float* eWih = (const float*)d_in[1];
    const float* eWhh = (const float*)d_in[2];
    const float* ebih = (const float*)d_in[3];
    const float* ebhh = (const float*)d_in[4];
    const float* dWih = (const float*)d_in[5];
    const float* dWhh = (const float*)d_in[6];
    const float* dbih = (const float*)d_in[7];
    const float* dbhh = (const float*)d_in[8];
    const float* attnW= (const float*)d_in[9];
    const float* fcW  = (const float*)d_in[10];
    const float* fcb  = (const float*)d_in[11];
    float* out = (float*)d_out;

    char* base = (char*)d_ws;
    auto alloc = [&](size_t bytes){ void* p = base; base += (bytes + 255) & ~255ull; return p; };
    unsigned short* Wencf = (unsigned short*)alloc((size_t)256*KCE*512*2);
    float*          benc  = (float*)alloc(G4*4);
    unsigned short* Wdecf = (unsigned short*)alloc((size_t)256*KCD*512*2);
    float*          bdec  = (float*)alloc(G4*4);
    unsigned short* Wattf = (unsigned short*)alloc((size_t)64*KCQ*512*2);
    unsigned short* srcf  = (unsigned short*)alloc((size_t)Sn*8*2*512*2);
    unsigned short* enco  = (unsigned short*)alloc((size_t)Bn*Sn*Hn*2);
    unsigned short* hf0   = (unsigned short*)alloc((size_t)8*32*512*2);
    unsigned short* hf1   = (unsigned short*)alloc((size_t)8*32*512*2);
    float*          cbuf  = (float*)alloc((size_t)Bn*Hn*4);
    unsigned short* A0f   = (unsigned short*)alloc((size_t)8*KCD*512*2);
    unsigned short* A1f   = (unsigned short*)alloc((size_t)8*KCD*512*2);
    unsigned short* qbf   = (unsigned short*)alloc((size_t)Bn*Hn*2);

    conv_srcf<<<2048, 256, 0, stream>>>(src, srcf);
    pack_encf<<<4096, 256, 0, stream>>>(eWih, eWhh, ebih, ebhh, Wencf, benc);
    pack_decf<<<8192, 256, 0, stream>>>(dWih, dWhh, dbih, dbhh, Wdecf, bdec);
    pack_attnf<<<1024, 256, 0, stream>>>(attnW, Wattf);
    init_ws<<<1040, 256, 0, stream>>>(hf0, cbuf, A0f, A1f);

    unsigned short* hf[2] = {hf0, hf1};
    unsigned short* Ad[2] = {A0f, A1f};

    for (int t = 0; t < Sn; t++){
        enc_step<<<256, 128, 0, stream>>>(srcf, hf[t&1], Wencf, benc, cbuf,
                                          hf[(t+1)&1], enco, A0f, t, t == Sn-1);
    }
    for (int d = 0; d < Tn; d++){
        unsigned short* Ac = Ad[d&1];
        unsigned short* An = Ad[(d+1)&1];
        attnq_step<<<256, 128, 0, stream>>>(Ac, Wattf, qbf);
        fattn_kernel<<<Bn, 512, 0, stream>>>(qbf, enco, Ac, fcW, fcb, out, d);
        dec_step<<<256, 128, 0, stream>>>(Ac, Wdecf, bdec, cbuf, An);
    }
    fc_final<<<Bn, 128, 0, stream>>>(Ad[0], fcW, fcb, out);
}

// Round 9
// 9486.646 us; speedup vs baseline: 2.0074x; 1.0479x over previous
//
#include <hip/hip_runtime.h>
#include <math.h>

#define Bn   128
#define Sn   336
#define INd  64
#define Hn   1024
#define Tn   96
#define G4   4096
#define KCE  34     // enc k-chunks: [x(64) | h(1024)]
#define KCD  65     // dec k-chunks: [ctx(1024) | h(1024) | prev_y | pad]
#define KCQ  32     // attn query k-chunks

typedef __attribute__((ext_vector_type(8))) short short8;
typedef __attribute__((ext_vector_type(4))) float floatx4;
typedef __attribute__((ext_vector_type(4))) unsigned int uintx4;

__device__ __forceinline__ float sigmoidf_(float x){ return 1.0f/(1.0f+expf(-x)); }

__device__ __forceinline__ unsigned short f2bf(float f){
    union { float f; unsigned u; } v; v.f = f;
    unsigned r = v.u + 0x7fffu + ((v.u >> 16) & 1u);
    return (unsigned short)(r >> 16);
}
__device__ __forceinline__ float bflo(unsigned u){ union{unsigned u; float f;} v; v.u = u << 16;        return v.f; }
__device__ __forceinline__ float bfhi(unsigned u){ union{unsigned u; float f;} v; v.u = u & 0xffff0000u; return v.f; }
__device__ __forceinline__ void unpack8v(uintx4 v, float* f){
    f[0]=bflo(v.x); f[1]=bfhi(v.x); f[2]=bflo(v.y); f[3]=bfhi(v.y);
    f[4]=bflo(v.z); f[5]=bfhi(v.z); f[6]=bflo(v.w); f[7]=bfhi(v.w);
}

// ===================== fragment-order packing ==============================
__global__ void pack_encf(const float* __restrict__ Wih, const float* __restrict__ Whh,
                          const float* __restrict__ bih, const float* __restrict__ bhh,
                          unsigned short* __restrict__ Wp, float* __restrict__ bc){
    long n = (long)256*KCE*512;
    for (long idx = (long)blockIdx.x*256 + threadIdx.x; idx < n; idx += (long)gridDim.x*256){
        int j = (int)(idx & 7), l = (int)((idx >> 3) & 63);
        int kc = (int)((idx >> 9) % KCE);
        int s  = (int)(idx / (KCE*512));
        int c = l & 15, kg = l >> 4;
        int k = kc*32 + kg*8 + j;
        int gate = s & 3, unit = (s >> 2)*16 + c;
        int orig = gate*Hn + unit;
        float v = (k < INd) ? Wih[orig*INd + k] : Whh[(size_t)orig*Hn + (k - INd)];
        Wp[idx] = f2bf(v);
    }
    int tid = blockIdx.x*256 + threadIdx.x;
    if (tid < G4){
        int g = (tid >> 4) & 3, u = (tid >> 6)*16 + (tid & 15);
        int orig = g*Hn + u;
        bc[tid] = bih[orig] + bhh[orig];
    }
}

__global__ void pack_decf(const float* __restrict__ Wih, const float* __restrict__ Whh,
                          const float* __restrict__ bih, const float* __restrict__ bhh,
                          unsigned short* __restrict__ Wp, float* __restrict__ bc){
    long n = (long)256*KCD*512;
    for (long idx = (long)blockIdx.x*256 + threadIdx.x; idx < n; idx += (long)gridDim.x*256){
        int j = (int)(idx & 7), l = (int)((idx >> 3) & 63);
        int kc = (int)((idx >> 9) % KCD);
        int s  = (int)(idx / (KCD*512));
        int c = l & 15, kg = l >> 4;
        int k = kc*32 + kg*8 + j;
        int gate = s & 3, unit = (s >> 2)*16 + c;
        int orig = gate*Hn + unit;
        float v;
        if (k < Hn)          v = Wih[(size_t)orig*(Hn+1) + 1 + k];     // ctx
        else if (k < 2*Hn)   v = Whh[(size_t)orig*Hn + (k - Hn)];      // h
        else if (k == 2*Hn)  v = Wih[(size_t)orig*(Hn+1)];             // prev_y
        else                 v = 0.0f;                                  // pad
        Wp[idx] = f2bf(v);
    }
    int tid = blockIdx.x*256 + threadIdx.x;
    if (tid < G4){
        int g = (tid >> 4) & 3, u = (tid >> 6)*16 + (tid & 15);
        int orig = g*Hn + u;
        bc[tid] = bih[orig] + bhh[orig];
    }
}

__global__ void pack_attnf(const float* __restrict__ w, unsigned short* __restrict__ Wp){
    int n = 64*KCQ*512;
    for (int idx = blockIdx.x*256 + threadIdx.x; idx < n; idx += gridDim.x*256){
        int j = idx & 7, l = (idx >> 3) & 63;
        int kc = (idx >> 9) & 31;
        int s  = idx >> 14;
        int nn = s*16 + (l & 15);
        int k = kc*32 + (l >> 4)*8 + j;
        Wp[idx] = f2bf(w[(size_t)nn*Hn + k]);
    }
}

// src A-fragments: [t][rg(8)][kc(2)][lane][8]; row b = rg*16 + (l&15)
__global__ void conv_srcf(const float* __restrict__ s, unsigned short* __restrict__ d){
    int n = Sn*8*2*512;
    for (int idx = blockIdx.x*256 + threadIdx.x; idx < n; idx += gridDim.x*256){
        int j = idx & 7, l = (idx >> 3) & 63;
        int kc = (idx >> 9) & 1, rg = (idx >> 10) & 7, t = idx >> 13;
        int b = rg*16 + (l & 15);
        int k = kc*32 + (l >> 4)*8 + j;
        d[idx] = f2bf(s[((size_t)b*Sn + t)*INd + k]);
    }
}

__global__ void init_ws(unsigned short* __restrict__ hf0, float* __restrict__ cbuf,
                        unsigned short* __restrict__ A0, unsigned short* __restrict__ A1){
    for (int i = blockIdx.x*256 + threadIdx.x; i < 8*KCD*512; i += gridDim.x*256){
        A0[i] = 0; A1[i] = 0;
        if (i < 8*32*512) hf0[i] = 0;
        if (i < Bn*Hn) cbuf[i] = 0.0f;
    }
}

// XCD-aware swizzle: blocks on XCD k own y in [k*8, k*8+8) -> per-XCD weight
// slice (~1-2 MB) stays L2-resident across all recurrence steps.
__device__ __forceinline__ void swz(int b, int& x, int& y){
    int xcd = b & 7, li = b >> 3;
    y = xcd*8 + (li & 7);
    x = li >> 3;
}

// ===================== encoder step: 4 waves, split-K x2 ====================
// 256 thr: wave w -> (rgw = w&1, kh = w>>1). rg = x*2 + rgw.
// kh=1 computes chunks 17..33, dumps partials to LDS; kh=0 computes 0..16,
// adds partials, runs epilogue. All 4 SIMDs busy, per-wave chain halved.
__global__ __launch_bounds__(256)
void enc_step(const unsigned short* __restrict__ srcfrag,  // [336][8][2][512]
              const unsigned short* __restrict__ hin,      // [8][32][512]
              const unsigned short* __restrict__ Wf,       // [256][KCE][512]
              const float* __restrict__ bc, float* __restrict__ cbuf,
              unsigned short* __restrict__ hout,           // [8][32][512]
              unsigned short* __restrict__ enco,
              unsigned short* __restrict__ adec0,          // [8][KCD][512]
              int t, int last)
{
    __shared__ float red[2][16][65];
    const int tid = threadIdx.x, l = tid & 63, w = tid >> 6;
    const int rgw = w & 1, kh = w >> 1;
    int x, y; swz(blockIdx.x, x, y);
    const int rg = x*2 + rgw;
    const int m0 = rg*16;
    const unsigned short* Bf = Wf + (size_t)(4*y)*KCE*512 + l*8;
    const unsigned short* Ax = srcfrag + ((size_t)t*8 + rg)*2*512 + l*8;
    const unsigned short* Ah = hin + (size_t)rg*32*512 + l*8;
    floatx4 acc0={0,0,0,0}, acc1={0,0,0,0}, acc2={0,0,0,0}, acc3={0,0,0,0};

    if (kh == 0){
        #pragma unroll
        for (int kc = 0; kc < 2; kc++){
            short8 a  = *(const short8*)(Ax + kc*512);
            short8 b0 = *(const short8*)(Bf + (0*KCE + kc)*512);
            short8 b1 = *(const short8*)(Bf + (1*KCE + kc)*512);
            short8 b2 = *(const short8*)(Bf + (2*KCE + kc)*512);
            short8 b3 = *(const short8*)(Bf + (3*KCE + kc)*512);
            acc0 = __builtin_amdgcn_mfma_f32_16x16x32_bf16(a, b0, acc0, 0, 0, 0);
            acc1 = __builtin_amdgcn_mfma_f32_16x16x32_bf16(a, b1, acc1, 0, 0, 0);
            acc2 = __builtin_amdgcn_mfma_f32_16x16x32_bf16(a, b2, acc2, 0, 0, 0);
            acc3 = __builtin_amdgcn_mfma_f32_16x16x32_bf16(a, b3, acc3, 0, 0, 0);
        }
        #pragma unroll 5
        for (int hc = 0; hc < 15; hc++){
            short8 a  = *(const short8*)(Ah + hc*512);
            short8 b0 = *(const short8*)(Bf + (0*KCE + hc + 2)*512);
            short8 b1 = *(const short8*)(Bf + (1*KCE + hc + 2)*512);
            short8 b2 = *(const short8*)(Bf + (2*KCE + hc + 2)*512);
            short8 b3 = *(const short8*)(Bf + (3*KCE + hc + 2)*512);
            acc0 = __builtin_amdgcn_mfma_f32_16x16x32_bf16(a, b0, acc0, 0, 0, 0);
            acc1 = __builtin_amdgcn_mfma_f32_16x16x32_bf16(a, b1, acc1, 0, 0, 0);
            acc2 = __builtin_amdgcn_mfma_f32_16x16x32_bf16(a, b2, acc2, 0, 0, 0);
            acc3 = __builtin_amdgcn_mfma_f32_16x16x32_bf16(a, b3, acc3, 0, 0, 0);
        }
    } else {
        #pragma unroll 5
        for (int hc = 15; hc < 32; hc++){
            short8 a  = *(const short8*)(Ah + hc*512);
            short8 b0 = *(const short8*)(Bf + (0*KCE + hc + 2)*512);
            short8 b1 = *(const short8*)(Bf + (1*KCE + hc + 2)*512);
            short8 b2 = *(const short8*)(Bf + (2*KCE + hc + 2)*512);
            short8 b3 = *(const short8*)(Bf + (3*KCE + hc + 2)*512);
            acc0 = __builtin_amdgcn_mfma_f32_16x16x32_bf16(a, b0, acc0, 0, 0, 0);
            acc1 = __builtin_amdgcn_mfma_f32_16x16x32_bf16(a, b1, acc1, 0, 0, 0);
            acc2 = __builtin_amdgcn_mfma_f32_16x16x32_bf16(a, b2, acc2, 0, 0, 0);
            acc3 = __builtin_amdgcn_mfma_f32_16x16x32_bf16(a, b3, acc3, 0, 0, 0);
        }
        #pragma unroll
        for (int r = 0; r < 4; r++){
            red[rgw][ 0 + r][l] = acc0[r];
            red[rgw][ 4 + r][l] = acc1[r];
            red[rgw][ 8 + r][l] = acc2[r];
            red[rgw][12 + r][l] = acc3[r];
        }
    }
    __syncthreads();
    if (kh != 0) return;
    #pragma unroll
    for (int r = 0; r < 4; r++){
        acc0[r] += red[rgw][ 0 + r][l];
        acc1[r] += red[rgw][ 4 + r][l];
        acc2[r] += red[rgw][ 8 + r][l];
        acc3[r] += red[rgw][12 + r][l];
    }

    const int col = l & 15, q = l >> 4;
    const int u = y*16 + col;
    const float bi  = bc[y*64 + col];
    const float bf_ = bc[y*64 + 16 + col];
    const float bg  = bc[y*64 + 32 + col];
    const float bo  = bc[y*64 + 48 + col];
    const int lsh = ((u >> 3) & 3) * 16;
    #pragma unroll
    for (int r = 0; r < 4; r++){
        const int m = m0 + q*4 + r;
        float gi = acc0[r] + bi;
        float gf = acc1[r] + bf_;
        float gg = acc2[r] + bg;
        float go = acc3[r] + bo;
        float co = cbuf[(size_t)m*Hn + u];
        float cn = sigmoidf_(gf)*co + sigmoidf_(gi)*tanhf(gg);
        float hv = sigmoidf_(go)*tanhf(cn);
        cbuf[(size_t)m*Hn + u] = cn;
        unsigned short hb = f2bf(hv);
        const int lanep = (q*4 + r) + lsh;
        hout[(((size_t)rg*32 + (u >> 5))*64 + lanep)*8 + (u & 7)] = hb;
        __builtin_nontemporal_store(hb, enco + ((size_t)m*Sn + t)*Hn + u);
        if (last) adec0[(((size_t)rg*KCD + 32 + (u >> 5))*64 + lanep)*8 + (u & 7)] = hb;
    }
}

// ===================== decoder LSTM step: 4 waves, split-K x2 ===============
__global__ __launch_bounds__(256)
void dec_step(const unsigned short* __restrict__ Ac,       // [8][KCD][512]
              const unsigned short* __restrict__ Wf,       // [256][KCD][512]
              const float* __restrict__ bc, float* __restrict__ cbuf,
              unsigned short* __restrict__ An)              // next A h-slot
{
    __shared__ float red[2][16][65];
    const int tid = threadIdx.x, l = tid & 63, w = tid >> 6;
    const int rgw = w & 1, kh = w >> 1;
    int x, y; swz(blockIdx.x, x, y);
    const int rg = x*2 + rgw;
    const int m0 = rg*16;
    const unsigned short* Bf = Wf + (size_t)(4*y)*KCD*512 + l*8;
    const unsigned short* Af = Ac + (size_t)rg*KCD*512 + l*8;
    floatx4 acc0={0,0,0,0}, acc1={0,0,0,0}, acc2={0,0,0,0}, acc3={0,0,0,0};

    const int k0 = kh ? 33 : 0;
    const int k1 = kh ? KCD : 33;
    #pragma unroll 5
    for (int kc = k0; kc < k1; kc++){
        short8 a  = *(const short8*)(Af + kc*512);
        short8 b0 = *(const short8*)(Bf + (0*KCD + kc)*512);
        short8 b1 = *(const short8*)(Bf + (1*KCD + kc)*512);
        short8 b2 = *(const short8*)(Bf + (2*KCD + kc)*512);
        short8 b3 = *(const short8*)(Bf + (3*KCD + kc)*512);
        acc0 = __builtin_amdgcn_mfma_f32_16x16x32_bf16(a, b0, acc0, 0, 0, 0);
        acc1 = __builtin_amdgcn_mfma_f32_16x16x32_bf16(a, b1, acc1, 0, 0, 0);
        acc2 = __builtin_amdgcn_mfma_f32_16x16x32_bf16(a, b2, acc2, 0, 0, 0);
        acc3 = __builtin_amdgcn_mfma_f32_16x16x32_bf16(a, b3, acc3, 0, 0, 0);
    }
    if (kh != 0){
        #pragma unroll
        for (int r = 0; r < 4; r++){
            red[rgw][ 0 + r][l] = acc0[r];
            red[rgw][ 4 + r][l] = acc1[r];
            red[rgw][ 8 + r][l] = acc2[r];
            red[rgw][12 + r][l] = acc3[r];
        }
    }
    __syncthreads();
    if (kh != 0) return;
    #pragma unroll
    for (int r = 0; r < 4; r++){
        acc0[r] += red[rgw][ 0 + r][l];
        acc1[r] += red[rgw][ 4 + r][l];
        acc2[r] += red[rgw][ 8 + r][l];
        acc3[r] += red[rgw][12 + r][l];
    }

    const int col = l & 15, q = l >> 4;
    const int u = y*16 + col;
    const float bi  = bc[y*64 + col];
    const float bf_ = bc[y*64 + 16 + col];
    const float bg  = bc[y*64 + 32 + col];
    const float bo  = bc[y*64 + 48 + col];
    const int lsh = ((u >> 3) & 3) * 16;
    #pragma unroll
    for (int r = 0; r < 4; r++){
        const int m = m0 + q*4 + r;
        float gi = acc0[r] + bi;
        float gf = acc1[r] + bf_;
        float gg = acc2[r] + bg;
        float go = acc3[r] + bo;
        float co = cbuf[(size_t)m*Hn + u];
        float cn = sigmoidf_(gf)*co + sigmoidf_(gi)*tanhf(gg);
        float hv = sigmoidf_(go)*tanhf(cn);
        cbuf[(size_t)m*Hn + u] = cn;
        const int lanep = (q*4 + r) + lsh;
        An[(((size_t)rg*KCD + 32 + (u >> 5))*64 + lanep)*8 + (u & 7)] = f2bf(hv);
    }
}

// ===================== attention query GEMM: 4 waves, split-K x2 ===========
__global__ __launch_bounds__(256)
void attnq_step(const unsigned short* __restrict__ Ac, const unsigned short* __restrict__ Wf,
                unsigned short* __restrict__ qout)
{
    __shared__ float red[2][4][65];
    const int tid = threadIdx.x, l = tid & 63, w = tid >> 6;
    const int rgw = w & 1, kh = w >> 1;
    int x, y; swz(blockIdx.x, x, y);
    const int rg = x*2 + rgw;
    const int m0 = rg*16;
    const unsigned short* Bf = Wf + (size_t)y*KCQ*512 + l*8;
    const unsigned short* Af = Ac + ((size_t)rg*KCD + 32)*512 + l*8;
    floatx4 acc = {0,0,0,0};
    const int k0 = kh ? 16 : 0;
    const int k1 = kh ? 32 : 16;
    #pragma unroll 8
    for (int kc = k0; kc < k1; kc++){
        short8 a = *(const short8*)(Af + kc*512);
        short8 b = *(const short8*)(Bf + kc*512);
        acc = __builtin_amdgcn_mfma_f32_16x16x32_bf16(a, b, acc, 0, 0, 0);
    }
    if (kh != 0){
        #pragma unroll
        for (int r = 0; r < 4; r++) red[rgw][r][l] = acc[r];
    }
    __syncthreads();
    if (kh != 0) return;
    #pragma unroll
    for (int r = 0; r < 4; r++) acc[r] += red[rgw][r][l];

    const int col = l & 15, q = l >> 4;
    #pragma unroll
    for (int r = 0; r < 4; r++){
        const int m = m0 + q*4 + r;
        qout[(size_t)m*Hn + y*16 + col] = f2bf(acc[r]);
    }
}

// ===================== fused attention: online softmax + ctx + fc ==========
__global__ __launch_bounds__(512)
void fattn_kernel(const unsigned short* __restrict__ q,    // [128][1024]
                  const unsigned short* __restrict__ enc,  // [128][336][1024]
                  unsigned short* __restrict__ Ac,         // fragment A buffer
                  const float* __restrict__ fcW, const float* __restrict__ fcb,
                  float* __restrict__ out, int d)
{
    __shared__ float ctxl[8*1024];
    __shared__ float mred[8], lred[8];
    __shared__ float fcred[128];
    const int b = blockIdx.x;
    const int tid = threadIdx.x, w = tid >> 6, l = tid & 63;

    float qv[16];
    {
        const uintx4* qp = (const uintx4*)(q + (size_t)b*Hn) + l*2;
        uintx4 q0 = qp[0], q1 = qp[1];
        unpack8v(q0, qv); unpack8v(q1, qv + 8);
    }
    float m = -1e30f, lsum = 0.0f;
    float cacc[16];
    #pragma unroll
    for (int i = 0; i < 16; i++) cacc[i] = 0.0f;

    const uintx4* ebase = (const uintx4*)(enc + (size_t)b*Sn*Hn) + l*2;
    for (int s = w; s < Sn; s += 8){
        uintx4 e0 = __builtin_nontemporal_load(ebase + (size_t)s*128);
        uintx4 e1 = __builtin_nontemporal_load(ebase + (size_t)s*128 + 1);
        float ev[16];
        unpack8v(e0, ev); unpack8v(e1, ev + 8);
        float part = 0.0f;
        #pragma unroll
        for (int i = 0; i < 16; i++) part = fmaf(qv[i], ev[i], part);
        #pragma unroll
        for (int off = 32; off; off >>= 1) part += __shfl_down(part, off);
        float e = __shfl(part, 0);
        float mn = fmaxf(m, e);
        float corr = expf(m - mn);
        float p = expf(e - mn);
        lsum = lsum*corr + p;
        if (corr != 1.0f){
            #pragma unroll
            for (int i = 0; i < 16; i++) cacc[i] *= corr;
        }
        #pragma unroll
        for (int i = 0; i < 16; i++) cacc[i] = fmaf(p, ev[i], cacc[i]);
        m = mn;
    }
    if (l == 0){ mred[w] = m; lred[w] = lsum; }
    __syncthreads();
    float M = mred[0];
    #pragma unroll
    for (int k = 1; k < 8; k++) M = fmaxf(M, mred[k]);
    float corr = expf(m - M);
    #pragma unroll
    for (int j = 0; j < 16; j++) ctxl[w*1024 + j*64 + l] = cacc[j]*corr;
    __syncthreads();
    float L = 0.0f;
    #pragma unroll
    for (int k = 0; k < 8; k++) L += lred[k]*expf(mred[k] - M);
    float invL = 1.0f / L;

    {
        const int u0 = 2*tid;
        float s0 = 0.0f, s1 = 0.0f;
        #pragma unroll
        for (int k = 0; k < 8; k++){
            s0 += ctxl[k*1024 + (u0 & 15)*64 + (u0 >> 4)];
            s1 += ctxl[k*1024 + ((u0+1) & 15)*64 + ((u0+1) >> 4)];
        }
        ushort2 cv; cv.x = f2bf(s0*invL); cv.y = f2bf(s1*invL);
        const int kc = u0 >> 5;
        const int lanep = (b & 15) + ((u0 >> 3) & 3)*16;
        *(ushort2*)(Ac + ((((size_t)(b >> 4))*KCD + kc)*64 + lanep)*8 + (u0 & 7)) = cv;
    }

    float part = 0.0f;
    if (tid < 128){
        const unsigned short* hp = Ac + ((((size_t)(b >> 4))*KCD + 32 + (tid >> 2))*64
                                         + (b & 15) + (tid & 3)*16)*8;
        uintx4 hv = *(const uintx4*)hp;
        float hf[8]; unpack8v(hv, hf);
        #pragma unroll
        for (int j = 0; j < 8; j++) part = fmaf(hf[j], fcW[tid*8 + j], part);
    }
    __syncthreads();
    if (tid < 128) fcred[tid] = part;
    __syncthreads();
    for (int o = 64; o; o >>= 1){
        if (tid < o && tid + o < 128) fcred[tid] += fcred[tid + o];
        __syncthreads();
    }
    if (tid == 0 && d > 0){
        float p = fcred[0] + fcb[0];
        out[b*Tn + (d - 1)] = p;
        Ac[(((size_t)(b >> 4))*KCD + 64)*512 + (b & 15)*8] = f2bf(p);
    }
}

// ===================== final fc ============================================
__global__ __launch_bounds__(128)
void fc_final(const unsigned short* __restrict__ A, const float* __restrict__ fcW,
              const float* __restrict__ fcb, float* __restrict__ out){
    __shared__ float red[128];
    const int b = blockIdx.x, tid = threadIdx.x;
    const unsigned short* hp = A + ((((size_t)(b >> 4))*KCD + 32 + (tid >> 2))*64
                                     + (b & 15) + (tid & 3)*16)*8;
    uintx4 hv = *(const uintx4*)hp;
    float hf[8]; unpack8v(hv, hf);
    float part = 0.0f;
    #pragma unroll
    for (int j = 0; j < 8; j++) part = fmaf(hf[j], fcW[tid*8 + j], part);
    red[tid] = part; __syncthreads();
    for (int o = 64; o; o >>= 1){
        if (tid < o) red[tid] += red[tid + o];
        __syncthreads();
    }
    if (tid == 0) out[b*Tn + (Tn - 1)] = red[0] + fcb[0];
}

extern "C" void kernel_launch(void* const* d_in, const int* in_sizes, int n_in,
                              void* d_out, int out_size, void* d_ws, size_t ws_size,
                              hipStream_t stream){
    const float* src  = (const float*)d_in[0];
    const float* eWih = (const float*)d_in[1];
    const float* eWhh = (const float*)d_in[2];
    const float* ebih = (const float*)d_in[3];
    const float* ebhh = (const float*)d_in[4];
    const float* dWih = (const float*)d_in[5];
    const float* dWhh = (const float*)d_in[6];
    const float* dbih = (const float*)d_in[7];
    const float* dbhh = (const float*)d_in[8];
    const float* attnW= (const float*)d_in[9];
    const float* fcW  = (const float*)d_in[10];
    const float* fcb  = (const float*)d_in[11];
    float* out = (float*)d_out;

    char* base = (char*)d_ws;
    auto alloc = [&](size_t bytes){ void* p = base; base += (bytes + 255) & ~255ull; return p; };
    unsigned short* Wencf = (unsigned short*)alloc((size_t)256*KCE*512*2);
    float*          benc  = (float*)alloc(G4*4);
    unsigned short* Wdecf = (unsigned short*)alloc((size_t)256*KCD*512*2);
    float*          bdec  = (float*)alloc(G4*4);
    unsigned short* Wattf = (unsigned short*)alloc((size_t)64*KCQ*512*2);
    unsigned short* srcf  = (unsigned short*)alloc((size_t)Sn*8*2*512*2);
    unsigned short* enco  = (unsigned short*)alloc((size_t)Bn*Sn*Hn*2);
    unsigned short* hf0   = (unsigned short*)alloc((size_t)8*32*512*2);
    unsigned short* hf1   = (unsigned short*)alloc((size_t)8*32*512*2);
    float*          cbuf  = (float*)alloc((size_t)Bn*Hn*4);
    unsigned short* A0f   = (unsigned short*)alloc((size_t)8*KCD*512*2);
    unsigned short* A1f   = (unsigned short*)alloc((size_t)8*KCD*512*2);
    unsigned short* qbf   = (unsigned short*)alloc((size_t)Bn*Hn*2);

    conv_srcf<<<2048, 256, 0, stream>>>(src, srcf);
    pack_encf<<<4096, 256, 0, stream>>>(eWih, eWhh, ebih, ebhh, Wencf, benc);
    pack_decf<<<8192, 256, 0, stream>>>(dWih, dWhh, dbih, dbhh, Wdecf, bdec);
    pack_attnf<<<1024, 256, 0, stream>>>(attnW, Wattf);
    init_ws<<<1040, 256, 0, stream>>>(hf0, cbuf, A0f, A1f);

    unsigned short* hf[2] = {hf0, hf1};
    unsigned short* Ad[2] = {A0f, A1f};

    for (int t = 0; t < Sn; t++){
        enc_step<<<256, 256, 0, stream>>>(srcf, hf[t&1], Wencf, benc, cbuf,
                                          hf[(t+1)&1], enco, A0f, t, t == Sn-1);
    }
    for (int d = 0; d < Tn; d++){
        unsigned short* Ac = Ad[d&1];
        unsigned short* An = Ad[(d+1)&1];
        attnq_step<<<256, 256, 0, stream>>>(Ac, Wattf, qbf);
        fattn_kernel<<<Bn, 512, 0, stream>>>(qbf, enco, Ac, fcW, fcb, out, d);
        dec_step<<<256, 256, 0, stream>>>(Ac, Wdecf, bdec, cbuf, An);
    }
    fc_final<<<Bn, 128, 0, stream>>>(Ad[0], fcW, fcb, out);
}